// Round 1
// baseline (4169.981 us; speedup 1.0000x reference)
//
#include <hip/hip_runtime.h>
#include <stdint.h>

#define Hn 512
#define Dn 128
#define Nn 64
#define Tn 512
#define NT (Nn*Tn)   // 32768

typedef unsigned int uint;
typedef unsigned short ushort;

typedef __attribute__((ext_vector_type(4))) float f32x4;
typedef __attribute__((ext_vector_type(8))) short s16x8;

// ---------- ws layout (bytes) ----------
// emitb : 0x0000000  NT*Hn*2  = 32 MB   (emit bf16, overwritten in-place by B = exp(emit-rowmax))
// rm    : 0x2000000  NT*4     = 128 KB  (per-(n,t) rowmax, fp32)
// wmat  : 0x2020000  Hn*Dn*4  = 256 KB  (log p - log1p(-p))
// bias  : 0x2060000  Hn*4     = 2 KB    (sum_d log1p(-p))
// pt    : 0x2060800  Hn*Hn*2  = 512 KB  (P^T bf16: pt[c*Hn+k] = P[k][c])
// abuf  : 0x20E0800  2*4*16*Hn*2 = 128 KB (alpha exchange, double buffered, [buf][grp][seq][h])
// ctr   : 0x2100800  4*512*4  = 8 KB    (per-group per-step barrier counters)

__device__ inline float bf2f(ushort u) { union { uint i; float f; } v; v.i = uint(u) << 16; return v.f; }
__device__ inline ushort f2bf(float f) {
  union { uint i; float f; } v; v.f = f;
  uint u = v.i;
  uint r = (u + 0x7FFFu + ((u >> 16) & 1u)) >> 16;
  return ushort(r);
}

__global__ void k_zero(uint* ctr) {
  int i = blockIdx.x * 256 + threadIdx.x;
  if (i < 2048) ctr[i] = 0;
}

__global__ void k_prep(const float* __restrict__ py, float* __restrict__ wmat, float* __restrict__ bias) {
  int h = blockIdx.x;
  int d = threadIdx.x;
  float p = py[h * Dn + d];
  float lp = logf(p);
  float l1 = log1pf(-p);
  wmat[h * Dn + d] = lp - l1;
  float v = l1;
  for (int o = 1; o < 64; o <<= 1) v += __shfl_xor(v, o, 64);
  __shared__ float s2[2];
  if ((threadIdx.x & 63) == 0) s2[threadIdx.x >> 6] = v;
  __syncthreads();
  if (threadIdx.x == 0) bias[h] = s2[0] + s2[1];
}

// transpose probs_x -> pt bf16, pt[c*Hn + k] = P[k][c]
__global__ void k_pt(const float* __restrict__ px, ushort* __restrict__ pt) {
  __shared__ ushort sh[32][33];
  int tx = threadIdx.x, ty = threadIdx.y;
  sh[ty][tx] = f2bf(px[(blockIdx.y * 32 + ty) * Hn + blockIdx.x * 32 + tx]);
  __syncthreads();
  pt[(blockIdx.x * 32 + ty) * Hn + blockIdx.y * 32 + tx] = sh[tx][ty];
}

// emit[r][h] = sum_d seq[r][d]*wmat[h][d] + bias[h], bf16 out.  64x64 tile, K=128 full.
__global__ __launch_bounds__(256) void k_emit(const float* __restrict__ A, const float* __restrict__ wmat,
                                              const float* __restrict__ bias, ushort* __restrict__ eb) {
  __shared__ float As[Dn][64];   // [k][row]
  __shared__ float Bs[Dn][64];   // [k][col]
  int t = threadIdx.x;
  int r0 = blockIdx.y * 64, h0 = blockIdx.x * 64;
  int row = t >> 2, q = t & 3;
  for (int i = 0; i < 8; i++) {
    int ch = q + i * 4;  // 0..31 float4-chunks
    float4 a = *(const float4*)(A + (size_t)(r0 + row) * Dn + ch * 4);
    As[ch * 4 + 0][row] = a.x; As[ch * 4 + 1][row] = a.y;
    As[ch * 4 + 2][row] = a.z; As[ch * 4 + 3][row] = a.w;
    float4 b = *(const float4*)(wmat + (size_t)(h0 + row) * Dn + ch * 4);
    Bs[ch * 4 + 0][row] = b.x; Bs[ch * 4 + 1][row] = b.y;
    Bs[ch * 4 + 2][row] = b.z; Bs[ch * 4 + 3][row] = b.w;
  }
  __syncthreads();
  int tx = t & 15, ty = t >> 4;
  float acc[4][4] = {};
  for (int k = 0; k < Dn; k++) {
    float av[4], bv[4];
    *(float4*)av = *(const float4*)&As[k][ty * 4];
    *(float4*)bv = *(const float4*)&Bs[k][tx * 4];
#pragma unroll
    for (int ii = 0; ii < 4; ii++)
#pragma unroll
      for (int jj = 0; jj < 4; jj++) acc[ii][jj] += av[ii] * bv[jj];
  }
  float bsv[4];
  *(float4*)bsv = *(const float4*)(bias + h0 + tx * 4);
#pragma unroll
  for (int ii = 0; ii < 4; ii++) {
    int r = r0 + ty * 4 + ii;
    ushort4 u;
    u.x = f2bf(acc[ii][0] + bsv[0]); u.y = f2bf(acc[ii][1] + bsv[1]);
    u.z = f2bf(acc[ii][2] + bsv[2]); u.w = f2bf(acc[ii][3] + bsv[3]);
    *(ushort4*)(eb + (size_t)r * Hn + h0 + tx * 4) = u;
  }
}

__global__ void k_rowmax(const ushort* __restrict__ eb, float* __restrict__ rm) {
  int r = blockIdx.x, lane = threadIdx.x;
  uint4 u = *(const uint4*)(eb + (size_t)r * Hn + lane * 8);
  float m = bf2f(ushort(u.x & 0xffff));
  m = fmaxf(m, bf2f(ushort(u.x >> 16)));
  m = fmaxf(m, bf2f(ushort(u.y & 0xffff))); m = fmaxf(m, bf2f(ushort(u.y >> 16)));
  m = fmaxf(m, bf2f(ushort(u.z & 0xffff))); m = fmaxf(m, bf2f(ushort(u.z >> 16)));
  m = fmaxf(m, bf2f(ushort(u.w & 0xffff))); m = fmaxf(m, bf2f(ushort(u.w >> 16)));
  for (int o = 1; o < 64; o <<= 1) m = fmaxf(m, __shfl_xor(m, o, 64));
  if (lane == 0) rm[r] = m;
}

__global__ void k_bexp(ushort* __restrict__ eb, const float* __restrict__ rm) {
  int i = blockIdx.x * 256 + threadIdx.x;   // u32 index, total NT*Hn/2
  uint* p = (uint*)eb;
  uint u = p[i];
  float m = rm[i >> 8];
  float f0 = expf(bf2f(ushort(u & 0xffff)) - m);
  float f1 = expf(bf2f(ushort(u >> 16)) - m);
  p[i] = uint(f2bf(f0)) | (uint(f2bf(f1)) << 16);
}

__device__ inline void group_barrier(uint* c, uint target) {
  __syncthreads();
  if (threadIdx.x == 0) {
    __threadfence();   // release WG's global writes to device scope
    __hip_atomic_fetch_add(c, 1u, __ATOMIC_RELAXED, __HIP_MEMORY_SCOPE_AGENT);
    while (__hip_atomic_load(c, __ATOMIC_RELAXED, __HIP_MEMORY_SCOPE_AGENT) < target)
      __builtin_amdgcn_s_sleep(2);
    __threadfence();   // acquire: invalidate caches
  }
  __syncthreads();
}

// 64 WGs = 4 seq-groups x 16 col-groups (32 cols each), 128 threads (2 waves).
__global__ __launch_bounds__(128) void k_rec(
    const ushort* __restrict__ eb, const float* __restrict__ rm,
    const ushort* __restrict__ pt, const float* __restrict__ px,
    const int* __restrict__ lens, ushort* __restrict__ abuf,
    uint* __restrict__ ctr, float* __restrict__ outp) {
  const int bid = blockIdx.x;
  const int grp = bid >> 4;   // 0..3
  const int g = bid & 15;     // 0..15
  const int t = threadIdx.x;  // 0..127
  const int lane = t & 63, wv = t >> 6;

  __shared__ ushort Pf[2048 * 8];    // 32 KB: B-frags, frag f at byte f*16
  __shared__ ushort Al[16][520];     // alpha rows bf16, +8 pad
  __shared__ float bl[16][32];       // B values for this step's cols
  __shared__ ushort outs[16][32];    // output staging
  __shared__ float mloc[16], rcpl[16], Cacc[16], suml[16];
  __shared__ int lenl[16];

  if (t < 16) {
    lenl[t] = lens[grp * 16 + t];
    Cacc[t] = rm[(grp * 16 + t) * Tn + 0];
  }
  // stage P-slice into B-frag layout: cols [g*32, g*32+32), frag (kt, nt, ln)
  for (int i = 0; i < 16; i++) {
    int f = i * 128 + t;
    int kt = f >> 7, nt = (f >> 6) & 1, ln = f & 63;
    int c = g * 32 + nt * 16 + (ln & 15);
    int k0 = kt * 32 + (ln >> 4) * 8;
    uint4 v = *(const uint4*)(pt + (size_t)c * Hn + k0);
    *(uint4*)(&Pf[f * 8]) = v;
  }
  // init alpha (t=0): raw0 = px[0][h] * B[n][0][h]
  {
    int s = t >> 3, c4 = (t & 7) * 4;
    int h = g * 32 + c4;
    int n = grp * 16 + s;
    float4 p4 = *(const float4*)(px + h);
    ushort4 b4 = *(const ushort4*)(eb + ((size_t)n * Tn + 0) * Hn + h);
    outs[s][c4 + 0] = f2bf(p4.x * bf2f(b4.x));
    outs[s][c4 + 1] = f2bf(p4.y * bf2f(b4.y));
    outs[s][c4 + 2] = f2bf(p4.z * bf2f(b4.z));
    outs[s][c4 + 3] = f2bf(p4.w * bf2f(b4.w));
  }
  __syncthreads();
  if (t < 64) {
    int s = t >> 2, q = t & 3;
    uint4 v = *(const uint4*)(&outs[s][q * 8]);
    *(uint4*)(abuf + ((size_t)(0 * 4 + grp) * 16 + s) * Hn + g * 32 + q * 8) = v;
  }
  group_barrier(&ctr[grp * 512 + 0], 16);

  const int t_end = lenl[15];  // lengths sorted ascending -> max of group

  for (int ts = 1; ts < t_end; ts++) {
    const ushort* br = abuf + ((size_t)(((ts + 1) & 1) * 4 + grp) * 16) * Hn;
    ushort* bw = abuf + ((size_t)((ts & 1) * 4 + grp) * 16) * Hn;
    // stage full alpha block (16 seqs x 512) + per-seq max (whole wave covers one row per iter)
    for (int i = 0; i < 8; i++) {
      int cid = i * 128 + t;
      int s = cid >> 6, q = cid & 63;
      uint4 v = *(const uint4*)(br + (size_t)s * Hn + q * 8);
      *(uint4*)(&Al[s][q * 8]) = v;
      float m = bf2f(ushort(v.x & 0xffff));
      m = fmaxf(m, bf2f(ushort(v.x >> 16)));
      m = fmaxf(m, bf2f(ushort(v.y & 0xffff))); m = fmaxf(m, bf2f(ushort(v.y >> 16)));
      m = fmaxf(m, bf2f(ushort(v.z & 0xffff))); m = fmaxf(m, bf2f(ushort(v.z >> 16)));
      m = fmaxf(m, bf2f(ushort(v.w & 0xffff))); m = fmaxf(m, bf2f(ushort(v.w >> 16)));
      for (int o = 1; o < 64; o <<= 1) m = fmaxf(m, __shfl_xor(m, o, 64));
      if (lane == 0) mloc[s] = m;   // s = i*2 + wv, bijective over 16
    }
    __syncthreads();
    if (t < 16) rcpl[t] = 1.0f / mloc[t];
    // stage this step's B values (no scale; scale applied in epilogue)
    {
      int s = t >> 3, c4 = (t & 7) * 4;
      int n = grp * 16 + s;
      ushort4 b4 = *(const ushort4*)(eb + ((size_t)n * Tn + ts) * Hn + g * 32 + c4);
      bl[s][c4 + 0] = bf2f(b4.x); bl[s][c4 + 1] = bf2f(b4.y);
      bl[s][c4 + 2] = bf2f(b4.z); bl[s][c4 + 3] = bf2f(b4.w);
    }
    __syncthreads();
    // MFMA: wave wv -> n-tile wv; acc[s][c] = sum_k raw[s][k] * P[k][c]
    f32x4 acc = {0.f, 0.f, 0.f, 0.f};
    {
      int s_m = lane & 15, quad = lane >> 4;
#pragma unroll
      for (int kt = 0; kt < 16; kt++) {
        uint4 av = *(const uint4*)(&Al[s_m][kt * 32 + quad * 8]);
        uint4 bv = *(const uint4*)(&Pf[((kt * 2 + wv) * 64 + lane) * 8]);
        acc = __builtin_amdgcn_mfma_f32_16x16x32_bf16(
            __builtin_bit_cast(s16x8, av), __builtin_bit_cast(s16x8, bv), acc, 0, 0, 0);
      }
    }
    // epilogue: v = acc * B * (1/m); freeze finished seqs
    {
      int cl = wv * 16 + (lane & 15);
      int quad = lane >> 4;
#pragma unroll
      for (int r = 0; r < 4; r++) {
        int s = quad * 4 + r;
        float v = acc[r] * bl[s][cl] * rcpl[s];
        if (ts >= lenl[s]) v = bf2f(Al[s][g * 32 + cl]);
        outs[s][cl] = f2bf(v);
      }
    }
    if (g == 0 && t < 16 && ts < lenl[t])
      Cacc[t] += logf(mloc[t]) + rm[(grp * 16 + t) * Tn + ts];
    __syncthreads();
    if (t < 64) {
      int s = t >> 2, q = t & 3;
      uint4 v = *(const uint4*)(&outs[s][q * 8]);
      *(uint4*)(bw + (size_t)s * Hn + g * 32 + q * 8) = v;
    }
    group_barrier(&ctr[grp * 512 + ts], 16);
  }

  // finalize: out[n] = C + log(sum_h raw_final)
  if (g == 0) {
    const ushort* bf_ = abuf + ((size_t)(((t_end - 1) & 1) * 4 + grp) * 16) * Hn;
    for (int i = 0; i < 8; i++) {
      int cid = i * 128 + t;
      int s = cid >> 6, q = cid & 63;
      uint4 v = *(const uint4*)(bf_ + (size_t)s * Hn + q * 8);
      float a = bf2f(ushort(v.x & 0xffff)) + bf2f(ushort(v.x >> 16))
              + bf2f(ushort(v.y & 0xffff)) + bf2f(ushort(v.y >> 16))
              + bf2f(ushort(v.z & 0xffff)) + bf2f(ushort(v.z >> 16))
              + bf2f(ushort(v.w & 0xffff)) + bf2f(ushort(v.w >> 16));
      for (int o = 1; o < 64; o <<= 1) a += __shfl_xor(a, o, 64);
      if (lane == 0) suml[s] = a;
    }
    __syncthreads();
    if (t < 16) outp[grp * 16 + t] = Cacc[t] + logf(suml[t]);
  }
}

extern "C" void kernel_launch(void* const* d_in, const int* in_sizes, int n_in,
                              void* d_out, int out_size, void* d_ws, size_t ws_size,
                              hipStream_t stream) {
  const float* seq = (const float*)d_in[0];
  const int* lens = (const int*)d_in[1];
  const float* px = (const float*)d_in[2];
  const float* py = (const float*)d_in[3];
  char* ws = (char*)d_ws;
  ushort* emitb = (ushort*)(ws + 0x0000000);
  float* rm     = (float*)(ws + 0x2000000);
  float* wmat   = (float*)(ws + 0x2020000);
  float* bias   = (float*)(ws + 0x2060000);
  ushort* pt    = (ushort*)(ws + 0x2060800);
  ushort* abuf  = (ushort*)(ws + 0x20E0800);
  uint* ctr     = (uint*)(ws + 0x2100800);
  float* outp   = (float*)d_out;

  hipLaunchKernelGGL(k_zero, dim3(8), dim3(256), 0, stream, ctr);
  hipLaunchKernelGGL(k_prep, dim3(512), dim3(128), 0, stream, py, wmat, bias);
  hipLaunchKernelGGL(k_pt, dim3(16, 16), dim3(32, 32), 0, stream, px, pt);
  hipLaunchKernelGGL(k_emit, dim3(8, 512), dim3(256), 0, stream, seq, wmat, bias, emitb);
  hipLaunchKernelGGL(k_rowmax, dim3(NT), dim3(64), 0, stream, emitb, rm);
  hipLaunchKernelGGL(k_bexp, dim3(NT), dim3(256), 0, stream, emitb, rm);
  hipLaunchKernelGGL(k_rec, dim3(64), dim3(128), 0, stream, emitb, rm, pt, px, lens, abuf, ctr, outp);
}

// Round 2
// 2366.076 us; speedup vs baseline: 1.7624x; 1.7624x over previous
//
#include <hip/hip_runtime.h>
#include <stdint.h>

#define Hn 512
#define Dn 128
#define Nn 64
#define Tn 512
#define NT (Nn*Tn)   // 32768

typedef unsigned int uint;
typedef unsigned short ushort;
typedef unsigned long long u64;

typedef __attribute__((ext_vector_type(4))) float f32x4;
typedef __attribute__((ext_vector_type(8))) short s16x8;

// ---------- ws layout (bytes) ----------
// emitb : 0x0000000  NT*Hn*2  = 32 MB   (emit bf16, overwritten in-place by B = exp(emit-rowmax))
// rm    : 0x2000000  NT*4     = 128 KB  (per-(n,t) rowmax, fp32)
// wmat  : 0x2020000  Hn*Dn*4  = 256 KB  (log p - log1p(-p))
// bias  : 0x2060000  Hn*4     = 2 KB    (sum_d log1p(-p))
// pt    : 0x2060800  Hn*Hn*2  = 512 KB  (P^T bf16: pt[c*Hn+k] = P[k][c])
// abuf  : 0x20E0800  2*4*16*Hn*2 = 128 KB (alpha exchange, double buffered, [buf][grp][seq][h])
// flags : 0x2100800  4*128 B  (per-group 8 flag bytes, 128B-strided)

__device__ inline float bf2f(ushort u) { union { uint i; float f; } v; v.i = uint(u) << 16; return v.f; }
__device__ inline ushort f2bf(float f) {
  union { uint i; float f; } v; v.f = f;
  uint u = v.i;
  uint r = (u + 0x7FFFu + ((u >> 16) & 1u)) >> 16;
  return ushort(r);
}

// fence-free cross-XCD exchange: relaxed agent-scope atomics bypass L1/L2 -> LLC
__device__ inline u64 a64(const u64* p) {
  return __hip_atomic_load(p, __ATOMIC_RELAXED, __HIP_MEMORY_SCOPE_AGENT);
}
__device__ inline void s64(u64* p, u64 v) {
  __hip_atomic_store(p, v, __ATOMIC_RELAXED, __HIP_MEMORY_SCOPE_AGENT);
}
__device__ inline void sflag(unsigned char* p, unsigned char v) {
  __hip_atomic_store(p, v, __ATOMIC_RELAXED, __HIP_MEMORY_SCOPE_AGENT);
}

__global__ void k_zero(uint* ctr) {
  int i = blockIdx.x * 256 + threadIdx.x;
  if (i < 2048) ctr[i] = 0;
}

__global__ void k_prep(const float* __restrict__ py, float* __restrict__ wmat, float* __restrict__ bias) {
  int h = blockIdx.x;
  int d = threadIdx.x;
  float p = py[h * Dn + d];
  float lp = logf(p);
  float l1 = log1pf(-p);
  wmat[h * Dn + d] = lp - l1;
  float v = l1;
  for (int o = 1; o < 64; o <<= 1) v += __shfl_xor(v, o, 64);
  __shared__ float s2[2];
  if ((threadIdx.x & 63) == 0) s2[threadIdx.x >> 6] = v;
  __syncthreads();
  if (threadIdx.x == 0) bias[h] = s2[0] + s2[1];
}

// transpose probs_x -> pt bf16, pt[c*Hn + k] = P[k][c]
__global__ void k_pt(const float* __restrict__ px, ushort* __restrict__ pt) {
  __shared__ ushort sh[32][33];
  int tx = threadIdx.x, ty = threadIdx.y;
  sh[ty][tx] = f2bf(px[(blockIdx.y * 32 + ty) * Hn + blockIdx.x * 32 + tx]);
  __syncthreads();
  pt[(blockIdx.x * 32 + ty) * Hn + blockIdx.y * 32 + tx] = sh[tx][ty];
}

// emit[r][h] = sum_d seq[r][d]*wmat[h][d] + bias[h], bf16 out.  64x64 tile, K=128 full.
__global__ __launch_bounds__(256) void k_emit(const float* __restrict__ A, const float* __restrict__ wmat,
                                              const float* __restrict__ bias, ushort* __restrict__ eb) {
  __shared__ float As[Dn][64];   // [k][row]
  __shared__ float Bs[Dn][64];   // [k][col]
  int t = threadIdx.x;
  int r0 = blockIdx.y * 64, h0 = blockIdx.x * 64;
  int row = t >> 2, q = t & 3;
  for (int i = 0; i < 8; i++) {
    int ch = q + i * 4;
    float4 a = *(const float4*)(A + (size_t)(r0 + row) * Dn + ch * 4);
    As[ch * 4 + 0][row] = a.x; As[ch * 4 + 1][row] = a.y;
    As[ch * 4 + 2][row] = a.z; As[ch * 4 + 3][row] = a.w;
    float4 b = *(const float4*)(wmat + (size_t)(h0 + row) * Dn + ch * 4);
    Bs[ch * 4 + 0][row] = b.x; Bs[ch * 4 + 1][row] = b.y;
    Bs[ch * 4 + 2][row] = b.z; Bs[ch * 4 + 3][row] = b.w;
  }
  __syncthreads();
  int tx = t & 15, ty = t >> 4;
  float acc[4][4] = {};
  for (int k = 0; k < Dn; k++) {
    float av[4], bv[4];
    *(float4*)av = *(const float4*)&As[k][ty * 4];
    *(float4*)bv = *(const float4*)&Bs[k][tx * 4];
#pragma unroll
    for (int ii = 0; ii < 4; ii++)
#pragma unroll
      for (int jj = 0; jj < 4; jj++) acc[ii][jj] += av[ii] * bv[jj];
  }
  float bsv[4];
  *(float4*)bsv = *(const float4*)(bias + h0 + tx * 4);
#pragma unroll
  for (int ii = 0; ii < 4; ii++) {
    int r = r0 + ty * 4 + ii;
    ushort4 u;
    u.x = f2bf(acc[ii][0] + bsv[0]); u.y = f2bf(acc[ii][1] + bsv[1]);
    u.z = f2bf(acc[ii][2] + bsv[2]); u.w = f2bf(acc[ii][3] + bsv[3]);
    *(ushort4*)(eb + (size_t)r * Hn + h0 + tx * 4) = u;
  }
}

__global__ void k_rowmax(const ushort* __restrict__ eb, float* __restrict__ rm) {
  int r = blockIdx.x, lane = threadIdx.x;
  uint4 u = *(const uint4*)(eb + (size_t)r * Hn + lane * 8);
  float m = bf2f(ushort(u.x & 0xffff));
  m = fmaxf(m, bf2f(ushort(u.x >> 16)));
  m = fmaxf(m, bf2f(ushort(u.y & 0xffff))); m = fmaxf(m, bf2f(ushort(u.y >> 16)));
  m = fmaxf(m, bf2f(ushort(u.z & 0xffff))); m = fmaxf(m, bf2f(ushort(u.z >> 16)));
  m = fmaxf(m, bf2f(ushort(u.w & 0xffff))); m = fmaxf(m, bf2f(ushort(u.w >> 16)));
  for (int o = 1; o < 64; o <<= 1) m = fmaxf(m, __shfl_xor(m, o, 64));
  if (lane == 0) rm[r] = m;
}

__global__ void k_bexp(ushort* __restrict__ eb, const float* __restrict__ rm) {
  int i = blockIdx.x * 256 + threadIdx.x;
  uint* p = (uint*)eb;
  uint u = p[i];
  float m = rm[i >> 8];
  float f0 = expf(bf2f(ushort(u & 0xffff)) - m);
  float f1 = expf(bf2f(ushort(u >> 16)) - m);
  p[i] = uint(f2bf(f0)) | (uint(f2bf(f1)) << 16);
}

// 32 WGs = 4 seq-groups x 8 col-groups (64 cols each), 256 threads (4 waves).
// P-slice (64KB) lives in LDS in MFMA B-frag layout; alpha exchanged through
// LLC via relaxed agent atomics; per-step barrier = 8 flag bytes in one line.
__global__ __launch_bounds__(256) void k_rec(
    const ushort* __restrict__ eb, const float* __restrict__ rm,
    const ushort* __restrict__ pt, const float* __restrict__ px,
    const int* __restrict__ lens, ushort* __restrict__ abuf,
    unsigned char* __restrict__ flags, float* __restrict__ outp) {
  const int bid = blockIdx.x;
  const int grp = bid >> 3;   // 0..3
  const int g = bid & 7;      // 0..7
  const int t = threadIdx.x;  // 0..255
  const int lane = t & 63, wv = t >> 6;

  __shared__ ushort Pf[4096 * 8];    // 64 KB: B-frags, frag f at byte f*16
  __shared__ ushort Al[16][520];     // alpha rows bf16, +8 pad
  __shared__ float bl[16][64];       // B values for this step's cols
  __shared__ ushort outs[16][64];    // output staging
  __shared__ float mpart[16][2];     // per-row half maxima (reused as sums at end)
  __shared__ float mloc[16], rcpl[16], Cacc[16];
  __shared__ int lenl[16];

  if (t < 16) {
    lenl[t] = lens[grp * 16 + t];
    Cacc[t] = rm[(grp * 16 + t) * Tn];
  }
  // stage P-slice into B-frag layout: cols [g*64, g*64+64)
  for (int i = 0; i < 16; i++) {
    int f = i * 256 + t;
    int kt = f >> 8, nt = (f >> 6) & 3, ln = f & 63;
    int c = g * 64 + nt * 16 + (ln & 15);
    int k0 = kt * 32 + (ln >> 4) * 8;
    uint4 v = *(const uint4*)(pt + (size_t)c * Hn + k0);
    *(uint4*)(&Pf[f * 8]) = v;
  }
  // init alpha (t=0): raw0 = px[0][h] * B[n][0][h]
  {
    int s = t >> 4, c4 = (t & 15) * 4;
    int h = g * 64 + c4;
    int n = grp * 16 + s;
    float4 p4 = *(const float4*)(px + h);
    ushort4 b4 = *(const ushort4*)(eb + (size_t)n * Tn * Hn + h);
    outs[s][c4 + 0] = f2bf(p4.x * bf2f(b4.x));
    outs[s][c4 + 1] = f2bf(p4.y * bf2f(b4.y));
    outs[s][c4 + 2] = f2bf(p4.z * bf2f(b4.z));
    outs[s][c4 + 3] = f2bf(p4.w * bf2f(b4.w));
  }
  __syncthreads();
  {
    int s = t >> 4, q = t & 15;
    u64 v = *(u64*)(&outs[s][q * 4]);
    s64((u64*)(abuf + ((size_t)grp * 16 + s) * Hn + g * 64 + q * 4), v);
  }
  asm volatile("s_waitcnt vmcnt(0)" ::: "memory");
  __syncthreads();
  if (t == 0) sflag(&flags[grp * 128 + g], (unsigned char)1);
  const int t_end = lenl[15];  // lengths sorted -> group max
  // prefetch B-slice for ts=1
  ushort4 bpre;
  {
    int s = t >> 4, c4 = (t & 15) * 4;
    bpre = *(const ushort4*)(eb + ((size_t)(grp * 16 + s) * Tn + 1) * Hn + g * 64 + c4);
  }
  if (t == 0) {
    u64 tgt = 0x0101010101010101ULL;
    while (a64((const u64*)&flags[grp * 128]) != tgt) __builtin_amdgcn_s_sleep(1);
  }
  __syncthreads();

  for (int ts = 1; ts < t_end; ts++) {
    const ushort* br = abuf + ((size_t)(((ts + 1) & 1) * 4 + grp) * 16) * Hn;
    ushort* bw = abuf + ((size_t)((ts & 1) * 4 + grp) * 16) * Hn;
    // load full alpha block (16 seqs x 512) via LLC atomics, 8B per thread x8
    u64 va[8];
#pragma unroll
    for (int i = 0; i < 8; i++) {
      int cid = i * 256 + t;
      int s = cid >> 7, q = cid & 127;
      va[i] = a64((const u64*)(br + (size_t)s * Hn + q * 4));
    }
#pragma unroll
    for (int i = 0; i < 8; i++) {
      int cid = i * 256 + t;
      int s = cid >> 7, q = cid & 127;
      *(u64*)(&Al[s][q * 4]) = va[i];
    }
    // stage this step's B values from the prefetch registers
    {
      int s4 = t >> 4, c4 = (t & 15) * 4;
      bl[s4][c4 + 0] = bf2f(bpre.x); bl[s4][c4 + 1] = bf2f(bpre.y);
      bl[s4][c4 + 2] = bf2f(bpre.z); bl[s4][c4 + 3] = bf2f(bpre.w);
    }
    // per-row maxima (8 independent shuffle chains for ILP)
#pragma unroll
    for (int i = 0; i < 8; i++) {
      u64 v = va[i];
      float m = bf2f(ushort(v & 0xffff));
      m = fmaxf(m, bf2f(ushort((v >> 16) & 0xffff)));
      m = fmaxf(m, bf2f(ushort((v >> 32) & 0xffff)));
      m = fmaxf(m, bf2f(ushort((v >> 48) & 0xffff)));
      for (int o = 1; o < 64; o <<= 1) m = fmaxf(m, __shfl_xor(m, o, 64));
      if (lane == 0) mpart[i * 2 + (t >> 7)][(t >> 6) & 1] = m;
    }
    __syncthreads();
    if (t < 16) {
      float m = fmaxf(mpart[t][0], mpart[t][1]);
      mloc[t] = m;
      rcpl[t] = 1.0f / m;
      if (g == 0 && ts < lenl[t]) Cacc[t] += logf(m) + rm[(grp * 16 + t) * Tn + ts];
    }
    // MFMA: wave wv -> n-tile wv; acc[s][c] = sum_k raw[s][k] * P[k][c]
    f32x4 acc = {0.f, 0.f, 0.f, 0.f};
    {
      int s_m = lane & 15, quad = lane >> 4;
#pragma unroll
      for (int kt = 0; kt < 16; kt++) {
        uint4 av = *(const uint4*)(&Al[s_m][kt * 32 + quad * 8]);
        uint4 bv = *(const uint4*)(&Pf[((kt * 4 + wv) * 64 + lane) * 8]);
        acc = __builtin_amdgcn_mfma_f32_16x16x32_bf16(
            __builtin_bit_cast(s16x8, av), __builtin_bit_cast(s16x8, bv), acc, 0, 0, 0);
      }
    }
    __syncthreads();   // rcpl/mloc visible to all; Al reads complete
    // epilogue: v = acc * B * (1/m); freeze finished seqs
    {
      int cl = wv * 16 + (lane & 15);
      int quad = lane >> 4;
#pragma unroll
      for (int r = 0; r < 4; r++) {
        int s = quad * 4 + r;
        float v = acc[r] * bl[s][cl] * rcpl[s];
        if (ts >= lenl[s]) v = bf2f(Al[s][g * 64 + cl]);
        outs[s][cl] = f2bf(v);
      }
    }
    __syncthreads();
    {
      int s = t >> 4, q = t & 15;
      u64 v = *(u64*)(&outs[s][q * 4]);
      s64((u64*)(bw + (size_t)s * Hn + g * 64 + q * 4), v);
    }
    asm volatile("s_waitcnt vmcnt(0)" ::: "memory");
    __syncthreads();
    if (t == 0) sflag(&flags[grp * 128 + g], (unsigned char)(ts + 1));
    // prefetch next B-slice while waiting
    {
      int tn2 = (ts + 1 < Tn) ? ts + 1 : Tn - 1;
      int s = t >> 4, c4 = (t & 15) * 4;
      bpre = *(const ushort4*)(eb + ((size_t)(grp * 16 + s) * Tn + tn2) * Hn + g * 64 + c4);
    }
    if (t == 0) {
      u64 tgt = 0x0101010101010101ULL * (u64)((unsigned char)(ts + 1));
      while (a64((const u64*)&flags[grp * 128]) != tgt) __builtin_amdgcn_s_sleep(1);
    }
    __syncthreads();
  }

  // finalize: out[n] = C + log(sum_h raw_final)
  if (g == 0) {
    const ushort* bf_ = abuf + ((size_t)(((t_end - 1) & 1) * 4 + grp) * 16) * Hn;
#pragma unroll
    for (int i = 0; i < 8; i++) {
      int cid = i * 256 + t;
      int s = cid >> 7, q = cid & 127;
      u64 v = a64((const u64*)(bf_ + (size_t)s * Hn + q * 4));
      float a = bf2f(ushort(v & 0xffff)) + bf2f(ushort((v >> 16) & 0xffff))
              + bf2f(ushort((v >> 32) & 0xffff)) + bf2f(ushort((v >> 48) & 0xffff));
      for (int o = 1; o < 64; o <<= 1) a += __shfl_xor(a, o, 64);
      if (lane == 0) mpart[i * 2 + (t >> 7)][(t >> 6) & 1] = a;
    }
    __syncthreads();
    if (t < 16) outp[grp * 16 + t] = Cacc[t] + logf(mpart[t][0] + mpart[t][1]);
  }
}

extern "C" void kernel_launch(void* const* d_in, const int* in_sizes, int n_in,
                              void* d_out, int out_size, void* d_ws, size_t ws_size,
                              hipStream_t stream) {
  const float* seq = (const float*)d_in[0];
  const int* lens = (const int*)d_in[1];
  const float* px = (const float*)d_in[2];
  const float* py = (const float*)d_in[3];
  char* ws = (char*)d_ws;
  ushort* emitb = (ushort*)(ws + 0x0000000);
  float* rm     = (float*)(ws + 0x2000000);
  float* wmat   = (float*)(ws + 0x2020000);
  float* bias   = (float*)(ws + 0x2060000);
  ushort* pt    = (ushort*)(ws + 0x2060800);
  ushort* abuf  = (ushort*)(ws + 0x20E0800);
  uint* ctr     = (uint*)(ws + 0x2100800);
  float* outp   = (float*)d_out;

  hipLaunchKernelGGL(k_zero, dim3(8), dim3(256), 0, stream, ctr);
  hipLaunchKernelGGL(k_prep, dim3(512), dim3(128), 0, stream, py, wmat, bias);
  hipLaunchKernelGGL(k_pt, dim3(16, 16), dim3(32, 32), 0, stream, px, pt);
  hipLaunchKernelGGL(k_emit, dim3(8, 512), dim3(256), 0, stream, seq, wmat, bias, emitb);
  hipLaunchKernelGGL(k_rowmax, dim3(NT), dim3(64), 0, stream, emitb, rm);
  hipLaunchKernelGGL(k_bexp, dim3(NT), dim3(256), 0, stream, emitb, rm);
  hipLaunchKernelGGL(k_rec, dim3(32), dim3(256), 0, stream, emitb, rm, pt, px, lens, abuf,
                     (unsigned char*)ctr, outp);
}